// Round 4
// baseline (335.420 us; speedup 1.0000x reference)
//
#include <hip/hip_runtime.h>
#include <hip/hip_bf16.h>

#define BB 2
#define NN 384
#define TFD 22
#define POSD 32
#define TPROJ 33
#define CS 256
#define CZ 128
#define PI_F 3.14159265358979323846f

typedef __hip_bfloat16 bf16;
typedef __attribute__((ext_vector_type(8))) short short8;
typedef __attribute__((ext_vector_type(4))) float floatx4;

__device__ __forceinline__ float bfbits2f(unsigned short u) {
  unsigned v = ((unsigned)u) << 16;
  float f;
  __builtin_memcpy(&f, &v, 4);
  return f;
}
__device__ __forceinline__ unsigned short f2bf(float x) {
  bf16 h = __float2bfloat16(x);
  unsigned short u;
  __builtin_memcpy(&u, &h, 2);
  return u;
}
__device__ __forceinline__ bool probe_f32(const void* fm) {
  return *(const unsigned*)fm == 0x3F800000u;
}
__device__ __forceinline__ float ldf(const void* p, int j, bool f32) {
  return f32 ? ((const float*)p)[j] : bfbits2f(((const unsigned short*)p)[j]);
}

// ---- ws layout (float units) ----
#define TAB_OFF 0            // 2048*128 (tab incl. all three edge biases)
#define SEQ0_OFF 262144      // 768*256
#define EL_OFF 458752        // 768*128
#define ER_OFF 557056        // 768*128
#define P2_OFF 655360        // 1536 floats of biases/gains
#define WB_OFF 656896        // bf16 (ushort) weight region: 163840 ushorts
#define qBN1 0
#define qBN2 256
#define qGN 512
#define qBEN 768
#define qBE1 1024
#define qBE2 1152
#define qGE 1280
#define qBEE 1408
#define UB_WE1 0
#define UB_WE2 16384
#define UB_WN1 32768
#define UB_WN2 98304

#define NODE8_BLKS 96
#define TAB_BLKS 1024
#define CVT_BLKS 646
#define NODE_BLKS 48

struct InPtrs { const void* p[28]; };

// ================= prep: node8 + tab + cvt (unchanged from r3) =================
__global__ __launch_bounds__(256) void prep(InPtrs ip, const int* __restrict__ seq_idx,
                                            float* __restrict__ ws) {
  const bool f32 = probe_f32(ip.p[3]);
  const int blk = blockIdx.x;
  const int t = threadIdx.x;
  if (blk < NODE8_BLKS) {
    __shared__ float feat[8][88];
    const int bn0 = blk * 8;
    if (t < 128) {
      const int n = t >> 4, j = t & 15, bn = bn0 + n, b = bn / NN;
      const float fm = ldf(ip.p[3], bn, f32);
      const float idxv = (float)seq_idx[bn];
      const float ang = idxv * PI_F * powf(2056.0f, -(float)j * (1.0f / 16.0f));
      feat[n][j] = sinf(ang);
      feat[n][16 + j] = cosf(ang);
      const float tres = ldf(ip.p[2], b, f32) * fm;
      const float freq = expf(-(logf(10000.0f) * (1.0f / 15.0f)) * (float)j);
      feat[n][54 + j] = sinf(tres * freq);
      feat[n][70 + j] = cosf(tres * freq);
      if (j == 0) feat[n][86] = fm;
    }
    if (t < 176) {
      const int n = t / TFD, j = t - n * TFD;
      feat[n][32 + j] = ldf(ip.p[1], (bn0 + n) * TFD + j, f32);
    }
    __syncthreads();
    {
      const int c = t;
      const float bias = ldf(ip.p[5], c, f32) + ldf(ip.p[7], c, f32) + ldf(ip.p[9], c, f32);
      float acc[8];
#pragma unroll
      for (int n = 0; n < 8; ++n) acc[n] = bias;
      if (f32) {
        const float* w = (const float*)ip.p[4] + c * POSD;
#pragma unroll
        for (int k = 0; k < POSD; ++k) { const float wv = w[k];
#pragma unroll
          for (int n = 0; n < 8; ++n) acc[n] += feat[n][k] * wv; }
        const float* w2 = (const float*)ip.p[6] + c * TFD;
#pragma unroll
        for (int k = 0; k < TFD; ++k) { const float wv = w2[k];
#pragma unroll
          for (int n = 0; n < 8; ++n) acc[n] += feat[n][32 + k] * wv; }
        const float* w3 = (const float*)ip.p[8] + c * TPROJ;
#pragma unroll
        for (int k = 0; k < TPROJ; ++k) { const float wv = w3[k];
#pragma unroll
          for (int n = 0; n < 8; ++n) acc[n] += feat[n][54 + k] * wv; }
      } else {
        const unsigned short* w = (const unsigned short*)ip.p[4] + c * POSD;
#pragma unroll
        for (int k = 0; k < POSD; ++k) { const float wv = bfbits2f(w[k]);
#pragma unroll
          for (int n = 0; n < 8; ++n) acc[n] += feat[n][k] * wv; }
        const unsigned short* w2 = (const unsigned short*)ip.p[6] + c * TFD;
#pragma unroll
        for (int k = 0; k < TFD; ++k) { const float wv = bfbits2f(w2[k]);
#pragma unroll
          for (int n = 0; n < 8; ++n) acc[n] += feat[n][32 + k] * wv; }
        const unsigned short* w3 = (const unsigned short*)ip.p[8] + c * TPROJ;
#pragma unroll
        for (int k = 0; k < TPROJ; ++k) { const float wv = bfbits2f(w3[k]);
#pragma unroll
          for (int n = 0; n < 8; ++n) acc[n] += feat[n][54 + k] * wv; }
      }
#pragma unroll
      for (int n = 0; n < 8; ++n) ws[SEQ0_OFF + (bn0 + n) * CS + c] = acc[n];
    }
    {
      const int isR = t >> 7;
      const int c = t & 127;
      const int o1 = isR ? TFD : 0, o2 = isR ? TPROJ : 0;
      const int dst = isR ? ER_OFF : EL_OFF;
      float acc[8];
#pragma unroll
      for (int n = 0; n < 8; ++n) acc[n] = 0.0f;
      if (f32) {
        const float* w = (const float*)ip.p[18] + c * (2 * TFD) + o1;
#pragma unroll
        for (int k = 0; k < TFD; ++k) { const float wv = w[k];
#pragma unroll
          for (int n = 0; n < 8; ++n) acc[n] += feat[n][32 + k] * wv; }
        const float* w2 = (const float*)ip.p[20] + c * (2 * TPROJ) + o2;
#pragma unroll
        for (int k = 0; k < TPROJ; ++k) { const float wv = w2[k];
#pragma unroll
          for (int n = 0; n < 8; ++n) acc[n] += feat[n][54 + k] * wv; }
      } else {
        const unsigned short* w = (const unsigned short*)ip.p[18] + c * (2 * TFD) + o1;
#pragma unroll
        for (int k = 0; k < TFD; ++k) { const float wv = bfbits2f(w[k]);
#pragma unroll
          for (int n = 0; n < 8; ++n) acc[n] += feat[n][32 + k] * wv; }
        const unsigned short* w2 = (const unsigned short*)ip.p[20] + c * (2 * TPROJ) + o2;
#pragma unroll
        for (int k = 0; k < TPROJ; ++k) { const float wv = bfbits2f(w2[k]);
#pragma unroll
          for (int n = 0; n < 8; ++n) acc[n] += feat[n][54 + k] * wv; }
      }
#pragma unroll
      for (int n = 0; n < 8; ++n) ws[dst + (bn0 + n) * CZ + c] = acc[n];
    }
  } else if (blk < NODE8_BLKS + TAB_BLKS) {
    __shared__ float spe[2][POSD];
    const int r0 = (blk - NODE8_BLKS) * 2;
    const int rr = t >> 7, c = t & 127;
    if (c < 16) {
      float ang = (float)(r0 + rr - 1024) * PI_F * powf(2056.0f, -(float)c * (1.0f / 16.0f));
      spe[rr][c] = sinf(ang);
      spe[rr][c + 16] = cosf(ang);
    }
    __syncthreads();
    float acc = ldf(ip.p[17], c, f32) + ldf(ip.p[19], c, f32) + ldf(ip.p[21], c, f32);
    if (f32) {
      const float* w = (const float*)ip.p[16] + c * POSD;
#pragma unroll
      for (int k = 0; k < POSD; ++k) acc += spe[rr][k] * w[k];
    } else {
      const unsigned short* w = (const unsigned short*)ip.p[16] + c * POSD;
#pragma unroll
      for (int k = 0; k < POSD; ++k) acc += spe[rr][k] * bfbits2f(w[k]);
    }
    ws[TAB_OFF + (r0 + rr) * CZ + c] = acc;
  } else {
    const int idx = (blk - NODE8_BLKS - TAB_BLKS) * 256 + t;
    if (idx < 1536) {
      int src, off;
      if (idx < 256)       { src = 11; off = idx; }
      else if (idx < 512)  { src = 13; off = idx - 256; }
      else if (idx < 768)  { src = 14; off = idx - 512; }
      else if (idx < 1024) { src = 15; off = idx - 768; }
      else if (idx < 1152) { src = 23; off = idx - 1024; }
      else if (idx < 1280) { src = 25; off = idx - 1152; }
      else if (idx < 1408) { src = 26; off = idx - 1280; }
      else                 { src = 27; off = idx - 1408; }
      ws[P2_OFF + idx] = ldf(ip.p[src], off, f32);
    } else {
      const int j = idx - 1536;
      int src, loc;
      if (j < 16384)      { src = 22; loc = j; }
      else if (j < 32768) { src = 24; loc = j - 16384; }
      else if (j < 98304) { src = 10; loc = j - 32768; }
      else                { src = 12; loc = j - 98304; }
      const void* sp = ip.p[src];
      unsigned short* wb = (unsigned short*)(ws + WB_OFF);
      wb[j] = f32 ? f2bf(((const float*)sp)[loc]) : ((const unsigned short*)sp)[loc];
    }
  }
}

// ================= node MLP: standalone, 48 blocks x 16 rows (r3 structure) ==========
struct SMemN {
  unsigned short A0[16][CS + 8];
  unsigned short A1[16][CS + 8];
  float O[16][CS + 4];
  float Red[16][16];
  float RedQ[16][16];
  float Mu[16];
  float Rs[16];
};

__global__ __launch_bounds__(256) void node_mfma(const float* __restrict__ ws,
                                                 const void* __restrict__ fmraw,
                                                 void* __restrict__ outv) {
  __shared__ __align__(16) SMemN sm;
  const int t = threadIdx.x;
  const int wave = t >> 6, lane = t & 63, quad = lane >> 4, l16 = lane & 15;
  const float* P2 = ws + P2_OFF;
  const unsigned short* WB = (const unsigned short*)(ws + WB_OFF);
  const bool f32o = probe_f32(fmraw);
  const int row0 = blockIdx.x * 16;
  const unsigned short* W1 = WB + UB_WN1;
  const unsigned short* W2 = WB + UB_WN2;
  const float* seq0 = ws + SEQ0_OFF;
#pragma unroll
  for (int r = 0; r < 16; ++r)
    sm.A0[r][t] = f2bf(fmaxf(seq0[(row0 + r) * CS + t], 0.0f));
  __syncthreads();
  short8 af[8];
  floatx4 acc[4];
#pragma unroll
  for (int ks = 0; ks < 8; ++ks) af[ks] = *(const short8*)&sm.A0[l16][ks * 32 + quad * 8];
#pragma unroll
  for (int n = 0; n < 4; ++n) acc[n] = (floatx4){0.f, 0.f, 0.f, 0.f};
#pragma unroll
  for (int ntl = 0; ntl < 4; ++ntl) {
    const int n0 = wave * 64 + ntl * 16;
#pragma unroll
    for (int ks = 0; ks < 8; ++ks) {
      short8 bfr = *(const short8*)&W1[(n0 + l16) * CS + ks * 32 + quad * 8];
      acc[ntl] = __builtin_amdgcn_mfma_f32_16x16x32_bf16(af[ks], bfr, acc[ntl], 0, 0, 0);
    }
  }
#pragma unroll
  for (int ntl = 0; ntl < 4; ++ntl) {
    const int n0 = wave * 64 + ntl * 16;
    const float b1v = P2[qBN1 + n0 + l16];
#pragma unroll
    for (int i = 0; i < 4; ++i)
      sm.A1[quad * 4 + i][n0 + l16] = f2bf(fmaxf(acc[ntl][i] + b1v, 0.0f));
  }
  __syncthreads();
#pragma unroll
  for (int ks = 0; ks < 8; ++ks) af[ks] = *(const short8*)&sm.A1[l16][ks * 32 + quad * 8];
#pragma unroll
  for (int n = 0; n < 4; ++n) acc[n] = (floatx4){0.f, 0.f, 0.f, 0.f};
#pragma unroll
  for (int ntl = 0; ntl < 4; ++ntl) {
    const int n0 = wave * 64 + ntl * 16;
#pragma unroll
    for (int ks = 0; ks < 8; ++ks) {
      short8 bfr = *(const short8*)&W2[(n0 + l16) * CS + ks * 32 + quad * 8];
      acc[ntl] = __builtin_amdgcn_mfma_f32_16x16x32_bf16(af[ks], bfr, acc[ntl], 0, 0, 0);
    }
  }
#pragma unroll
  for (int ntl = 0; ntl < 4; ++ntl) {
    const int n0 = wave * 64 + ntl * 16;
    const float b2v = P2[qBN2 + n0 + l16];
#pragma unroll
    for (int i = 0; i < 4; ++i)
      sm.O[quad * 4 + i][n0 + l16] = acc[ntl][i] + b2v;
  }
  __syncthreads();
  {
    const int r = t >> 4, seg = t & 15;
    float s = 0.f, q = 0.f;
#pragma unroll
    for (int k = 0; k < 16; ++k) { float v = sm.O[r][seg * 16 + k]; s += v; q += v * v; }
    sm.Red[r][seg] = s;
    sm.RedQ[r][seg] = q;
  }
  __syncthreads();
  if (t < 16) {
    float s = 0.f, q = 0.f;
#pragma unroll
    for (int k = 0; k < 16; ++k) { s += sm.Red[t][k]; q += sm.RedQ[t][k]; }
    float mu = s * (1.0f / CS);
    float var = q * (1.0f / CS) - mu * mu;
    sm.Mu[t] = mu;
    sm.Rs[t] = rsqrtf(var + 1e-5f);
  }
  __syncthreads();
  {
    const float g = P2[qGN + t], be = P2[qBEN + t];
    if (f32o) {
      float* o = (float*)outv;
#pragma unroll
      for (int r = 0; r < 16; ++r)
        o[(size_t)(row0 + r) * CS + t] = (sm.O[r][t] - sm.Mu[r]) * sm.Rs[r] * g + be;
    } else {
      bf16* o = (bf16*)outv;
#pragma unroll
      for (int r = 0; r < 16; ++r)
        o[(size_t)(row0 + r) * CS + t] =
            __float2bfloat16((sm.O[r][t] - sm.Mu[r]) * sm.Rs[r] * g + be);
    }
  }
}

// ============== edge MLP: per-wave independent, ZERO barriers, 768 blocks ==============
// Block = (b, irow). Wave w handles j-tile pairs {it*8 + w*2, it*8 + w*2 + 1}, it=0..2.
// A-fragments staged global->regs in MFMA layout; B-fragments from L2-hot bf16 weights
// (shared across the 2 tiles); layer1->layer2 transpose via wave-private XOR-swizzled
// 4KB LDS scratch (same-wave coherent: no barrier); LN in-register via 16-lane shfl_xor;
// stores straight from accumulators. No __syncthreads => no per-tile store drains.
__global__ __launch_bounds__(256) void edge_pw(const int* __restrict__ seq_idx,
                                               const float* __restrict__ ws,
                                               const void* __restrict__ fmraw,
                                               void* __restrict__ outv) {
  __shared__ __align__(16) unsigned char scrb[4][4096];  // per-wave [16 rows][128 cols] bf16
  const int t = threadIdx.x;
  const int wave = t >> 6, lane = t & 63, quad = lane >> 4, l16 = lane & 15;
  const float* P2 = ws + P2_OFF;
  const unsigned short* WB = (const unsigned short*)(ws + WB_OFF);
  const unsigned short* W1 = WB + UB_WE1;
  const unsigned short* W2 = WB + UB_WE2;
  const float* tab = ws + TAB_OFF;
  const bool f32o = probe_f32(fmraw);

  const int eb = blockIdx.x;
  const int irow = eb % NN, b = eb / NN;
  const int idx_i = seq_idx[b * NN + irow];
  const float* el = ws + EL_OFF + (size_t)(b * NN + irow) * CZ;
  const float* eRb = ws + ER_OFF + (size_t)b * NN * CZ;
  const size_t base0 = ((size_t)(b * NN + irow) * NN) * CZ;
  unsigned char* scrw = &scrb[wave][0];

  for (int it = 0; it < 3; ++it) {
    // ---- stage: A0 fragments direct to registers (relu(tab[rel] + eL + eR) in bf16) ----
    short8 af[2][4];
    int jbase[2];
#pragma unroll
    for (int mt = 0; mt < 2; ++mt) {
      const int j0 = (it * 8 + wave * 2 + mt) * 16;
      jbase[mt] = j0;
      const int jv = seq_idx[b * NN + j0 + l16];
      int rel = idx_i - jv + 1024;
      rel = min(max(rel, 0), 2047);
      const float* tr = tab + (size_t)rel * CZ;
      const float* er = eRb + (size_t)(j0 + l16) * CZ;
#pragma unroll
      for (int ks = 0; ks < 4; ++ks) {
        const int c = ks * 32 + quad * 8;
        const floatx4 t0 = *(const floatx4*)&tr[c];
        const floatx4 t1 = *(const floatx4*)&tr[c + 4];
        const floatx4 r0 = *(const floatx4*)&er[c];
        const floatx4 r1 = *(const floatx4*)&er[c + 4];
        const floatx4 l0 = *(const floatx4*)&el[c];
        const floatx4 l1 = *(const floatx4*)&el[c + 4];
        short8 v;
#pragma unroll
        for (int u = 0; u < 4; ++u) v[u] = (short)f2bf(fmaxf(t0[u] + r0[u] + l0[u], 0.0f));
#pragma unroll
        for (int u = 0; u < 4; ++u) v[4 + u] = (short)f2bf(fmaxf(t1[u] + r1[u] + l1[u], 0.0f));
        af[mt][ks] = v;
      }
    }
    // ---- layer 1: B from L2 weights, shared across the 2 m-tiles ----
    floatx4 acc[2][8];
#pragma unroll
    for (int mt = 0; mt < 2; ++mt)
#pragma unroll
      for (int n = 0; n < 8; ++n) acc[mt][n] = (floatx4){0.f, 0.f, 0.f, 0.f};
#pragma unroll
    for (int ntl = 0; ntl < 8; ++ntl) {
      const unsigned short* wrow = W1 + (size_t)(ntl * 16 + l16) * CZ;
#pragma unroll
      for (int ks = 0; ks < 4; ++ks) {
        const short8 bfr = *(const short8*)&wrow[ks * 32 + quad * 8];
        acc[0][ntl] = __builtin_amdgcn_mfma_f32_16x16x32_bf16(af[0][ks], bfr, acc[0][ntl], 0, 0, 0);
        acc[1][ntl] = __builtin_amdgcn_mfma_f32_16x16x32_bf16(af[1][ks], bfr, acc[1][ntl], 0, 0, 0);
      }
    }
    // ---- bias+relu -> wave-private XOR-swizzled scratch -> layer-2 A fragments ----
    short8 af2[2][4];
#pragma unroll
    for (int mt = 0; mt < 2; ++mt) {
#pragma unroll
      for (int ntl = 0; ntl < 8; ++ntl) {
        const float b1v = P2[qBE1 + ntl * 16 + l16];
        const int colb = (ntl * 16 + l16) * 2;
#pragma unroll
        for (int i = 0; i < 4; ++i) {
          const int row = quad * 4 + i;
          *(unsigned short*)&scrw[row * 256 + (colb ^ ((row & 7) << 4))] =
              f2bf(fmaxf(acc[mt][ntl][i] + b1v, 0.0f));
        }
      }
#pragma unroll
      for (int ks = 0; ks < 4; ++ks)
        af2[mt][ks] =
            *(const short8*)&scrw[l16 * 256 + ((ks * 64 + quad * 16) ^ ((l16 & 7) << 4))];
    }
    // ---- layer 2 ----
#pragma unroll
    for (int mt = 0; mt < 2; ++mt)
#pragma unroll
      for (int n = 0; n < 8; ++n) acc[mt][n] = (floatx4){0.f, 0.f, 0.f, 0.f};
#pragma unroll
    for (int ntl = 0; ntl < 8; ++ntl) {
      const unsigned short* wrow = W2 + (size_t)(ntl * 16 + l16) * CZ;
#pragma unroll
      for (int ks = 0; ks < 4; ++ks) {
        const short8 bfr = *(const short8*)&wrow[ks * 32 + quad * 8];
        acc[0][ntl] = __builtin_amdgcn_mfma_f32_16x16x32_bf16(af2[0][ks], bfr, acc[0][ntl], 0, 0, 0);
        acc[1][ntl] = __builtin_amdgcn_mfma_f32_16x16x32_bf16(af2[1][ks], bfr, acc[1][ntl], 0, 0, 0);
      }
    }
    // ---- bias + in-register LayerNorm (16-lane shfl reduce) + store from registers ----
#pragma unroll
    for (int mt = 0; mt < 2; ++mt) {
      float s[4] = {0.f, 0.f, 0.f, 0.f}, q[4] = {0.f, 0.f, 0.f, 0.f};
#pragma unroll
      for (int ntl = 0; ntl < 8; ++ntl) {
        const float b2v = P2[qBE2 + ntl * 16 + l16];
#pragma unroll
        for (int i = 0; i < 4; ++i) {
          const float v = acc[mt][ntl][i] + b2v;
          acc[mt][ntl][i] = v;
          s[i] += v;
          q[i] += v * v;
        }
      }
#pragma unroll
      for (int m = 1; m <= 8; m <<= 1) {
#pragma unroll
        for (int i = 0; i < 4; ++i) {
          s[i] += __shfl_xor(s[i], m);
          q[i] += __shfl_xor(q[i], m);
        }
      }
      float mu[4], rs[4];
#pragma unroll
      for (int i = 0; i < 4; ++i) {
        mu[i] = s[i] * (1.0f / CZ);
        rs[i] = rsqrtf(q[i] * (1.0f / CZ) - mu[i] * mu[i] + 1e-5f);
      }
      const int j0 = jbase[mt];
      if (f32o) {
        float* o = (float*)outv + (size_t)BB * NN * CS;
#pragma unroll
        for (int ntl = 0; ntl < 8; ++ntl) {
          const float g = P2[qGE + ntl * 16 + l16];
          const float be = P2[qBEE + ntl * 16 + l16];
#pragma unroll
          for (int i = 0; i < 4; ++i)
            o[base0 + (size_t)(j0 + quad * 4 + i) * CZ + ntl * 16 + l16] =
                (acc[mt][ntl][i] - mu[i]) * rs[i] * g + be;
        }
      } else {
        bf16* o = (bf16*)outv + (size_t)BB * NN * CS;
#pragma unroll
        for (int ntl = 0; ntl < 8; ++ntl) {
          const float g = P2[qGE + ntl * 16 + l16];
          const float be = P2[qBEE + ntl * 16 + l16];
#pragma unroll
          for (int i = 0; i < 4; ++i)
            o[base0 + (size_t)(j0 + quad * 4 + i) * CZ + ntl * 16 + l16] =
                __float2bfloat16((acc[mt][ntl][i] - mu[i]) * rs[i] * g + be);
        }
      }
    }
  }
}

extern "C" void kernel_launch(void* const* d_in, const int* in_sizes, int n_in,
                              void* d_out, int out_size, void* d_ws, size_t ws_size,
                              hipStream_t stream) {
  (void)in_sizes; (void)n_in; (void)out_size; (void)ws_size;
  const int* seq_idx = (const int*)d_in[0];
  float* ws = (float*)d_ws;
  InPtrs ip;
  for (int i = 0; i < 28; ++i) ip.p[i] = d_in[i];
  hipLaunchKernelGGL(prep, dim3(NODE8_BLKS + TAB_BLKS + CVT_BLKS), dim3(256), 0, stream,
                     ip, seq_idx, ws);
  hipLaunchKernelGGL(node_mfma, dim3(NODE_BLKS), dim3(256), 0, stream, ws, d_in[3], d_out);
  hipLaunchKernelGGL(edge_pw, dim3(BB * NN), dim3(256), 0, stream, seq_idx, ws, d_in[3], d_out);
}